// Round 3
// baseline (1422.704 us; speedup 1.0000x reference)
//
#include <hip/hip_runtime.h>

typedef short bf16x8 __attribute__((ext_vector_type(8)));
typedef float f32x4 __attribute__((ext_vector_type(4)));

__device__ __forceinline__ unsigned short f2bf_rn(float x) {
    unsigned int u = __float_as_uint(x);
    unsigned int r = u + 0x7FFF + ((u >> 16) & 1);
    return (unsigned short)(r >> 16);
}
__device__ __forceinline__ float bf2f(unsigned short h) {
    return __uint_as_float(((unsigned int)h) << 16);
}

// ================= Bucketed CSR build =================
// bucket b = dst >> 7 (128 nodes per bucket).

__global__ __launch_bounds__(256) void bucket_hist(const int* __restrict__ ei,
                                                   int* __restrict__ bcnt, int E, int NB) {
    __shared__ int h[1024];
    for (int i = threadIdx.x; i < NB; i += 256) h[i] = 0;
    __syncthreads();
    for (int e = blockIdx.x * blockDim.x + threadIdx.x; e < E; e += gridDim.x * blockDim.x) {
        atomicAdd(&h[ei[E + e] >> 7], 1);
    }
    __syncthreads();
    for (int i = threadIdx.x; i < NB; i += 256) {
        int v = h[i];
        if (v) atomicAdd(&bcnt[i], v);
    }
}

// single block: exclusive scan of bcnt[NB] -> bbase, init bcur, set sentinels
__global__ __launch_bounds__(1024) void bucket_scan(const int* __restrict__ bcnt,
                                                    int* __restrict__ bbase,
                                                    int* __restrict__ bcur,
                                                    int* __restrict__ offs,
                                                    int NB, int NN, int E) {
    __shared__ int s[1024];
    int t = threadIdx.x;
    int v = (t < NB) ? bcnt[t] : 0;
    s[t] = v;
    __syncthreads();
    for (int off = 1; off < 1024; off <<= 1) {
        int u = (t >= off) ? s[t - off] : 0;
        __syncthreads();
        s[t] += u;
        __syncthreads();
    }
    if (t < NB) {
        int base = s[t] - v;     // exclusive
        bbase[t] = base;
        bcur[t] = base;
    }
    if (t == 0) {
        bbase[NB] = E;
        offs[NN] = E;
    }
}

// scatter edges into bucket-major packed array: epk[p] = (dst<<32)|src
__global__ __launch_bounds__(256) void bucket_scatter(const int* __restrict__ ei,
                                                      int* __restrict__ bcur,
                                                      unsigned long long* __restrict__ epk,
                                                      int E) {
    for (int e = blockIdx.x * blockDim.x + threadIdx.x; e < E; e += gridDim.x * blockDim.x) {
        int s = ei[e];
        int d = ei[E + e];
        int p = atomicAdd(&bcur[d >> 7], 1);
        epk[p] = ((unsigned long long)(unsigned)d << 32) | (unsigned)s;
    }
}

// one block per bucket: local histogram + scan -> offs/dinv, then ordered srt writes
__global__ __launch_bounds__(256) void bucket_build(const unsigned long long* __restrict__ epk,
                                                    const int* __restrict__ bbase,
                                                    int* __restrict__ offs,
                                                    float* __restrict__ dinv,
                                                    int* __restrict__ srt,
                                                    int NN) {
    __shared__ int lcnt[128];
    __shared__ int sc[128];
    __shared__ int lcur[128];
    int b = blockIdx.x;
    int tid = threadIdx.x;
    int base = bbase[b], endp = bbase[b + 1];
    int ne = endp - base;
    int v0 = b << 7;
    int nv = NN - v0; if (nv > 128) nv = 128;

    if (tid < 128) lcnt[tid] = 0;
    __syncthreads();
    for (int i = tid; i < ne; i += 256) {
        int d = (int)(epk[base + i] >> 32);
        atomicAdd(&lcnt[d - v0], 1);
    }
    __syncthreads();
    // exclusive scan of lcnt over 128 entries
    if (tid < 128) sc[tid] = lcnt[tid];
    __syncthreads();
    for (int off = 1; off < 128; off <<= 1) {
        int u = (tid < 128 && tid >= off) ? sc[tid - off] : 0;
        __syncthreads();
        if (tid < 128) sc[tid] += u;
        __syncthreads();
    }
    if (tid < nv) {
        int ex = sc[tid] - lcnt[tid];
        offs[v0 + tid] = base + ex;
        lcur[tid] = base + ex;
        dinv[v0 + tid] = rsqrtf((float)(lcnt[tid] + 1));
    }
    __syncthreads();
    for (int i = tid; i < ne; i += 256) {
        unsigned long long pk = epk[base + i];
        int d = (int)(pk >> 32);
        int s = (int)(pk & 0xffffffffu);
        int p = atomicAdd(&lcur[d - v0], 1);
        srt[p] = s;
    }
}

// ---------------- W pre-split: W[K][128] fp32 -> Wt_hi/Wt_lo[col][K] bf16 ----------------
__global__ void wt_prep(const float* __restrict__ W, unsigned short* __restrict__ hi,
                        unsigned short* __restrict__ lo, int K) {
    int idx = blockIdx.x * 256 + threadIdx.x;
    if (idx >= K * 128) return;
    int k = idx >> 7;
    int c = idx & 127;
    float x = W[idx];
    unsigned short h = f2bf_rn(x);
    unsigned short l = f2bf_rn(x - bf2f(h));
    hi[(size_t)c * K + k] = h;
    lo[(size_t)c * K + k] = l;
}

// ---------------- MFMA GEMM (split-bf16): G = (X@W) * dinv[row] ----------------
template <int K>
__global__ __launch_bounds__(256) void gemm_mfma(const float* __restrict__ X,
                                                 const unsigned short* __restrict__ Wt_hi,
                                                 const unsigned short* __restrict__ Wt_lo,
                                                 const float* __restrict__ dinv,
                                                 float* __restrict__ G, int n) {
    __shared__ unsigned short As_hi[128][40];
    __shared__ unsigned short As_lo[128][40];
    __shared__ unsigned short Bs_hi[128][40];
    __shared__ unsigned short Bs_lo[128][40];

    const int tid = threadIdx.x;
    const int wave = tid >> 6;
    const int lane = tid & 63;
    const int l15 = lane & 15;
    const int l4 = lane >> 4;
    const int row0 = blockIdx.x * 128;
    const int wr0 = wave * 32;

    f32x4 acc[2][8];
#pragma unroll
    for (int i = 0; i < 2; ++i)
#pragma unroll
        for (int j = 0; j < 8; ++j) acc[i][j] = (f32x4){0.f, 0.f, 0.f, 0.f};

    const int sr = tid >> 1;
    const int sf = (tid & 1) * 16;

    for (int k0 = 0; k0 < K; k0 += 32) {
        __syncthreads();
        {
            int grow = row0 + sr;
            float4 v[4];
            if (grow < n) {
                const float* src = X + (size_t)grow * K + k0 + sf;
#pragma unroll
                for (int g = 0; g < 4; ++g) v[g] = *(const float4*)(src + g * 4);
            } else {
#pragma unroll
                for (int g = 0; g < 4; ++g) v[g] = make_float4(0.f, 0.f, 0.f, 0.f);
            }
#pragma unroll
            for (int g = 0; g < 4; ++g) {
                ushort4 h, l;
                h.x = f2bf_rn(v[g].x); l.x = f2bf_rn(v[g].x - bf2f(h.x));
                h.y = f2bf_rn(v[g].y); l.y = f2bf_rn(v[g].y - bf2f(h.y));
                h.z = f2bf_rn(v[g].z); l.z = f2bf_rn(v[g].z - bf2f(h.z));
                h.w = f2bf_rn(v[g].w); l.w = f2bf_rn(v[g].w - bf2f(h.w));
                *(ushort4*)&As_hi[sr][sf + g * 4] = h;
                *(ushort4*)&As_lo[sr][sf + g * 4] = l;
            }
        }
        {
#pragma unroll
            for (int rep = 0; rep < 2; ++rep) {
                int id = tid + rep * 256;
                int c = id >> 2;
                int q = (id & 3) * 8;
                *(uint4*)&Bs_hi[c][q] = *(const uint4*)&Wt_hi[(size_t)c * K + k0 + q];
                *(uint4*)&Bs_lo[c][q] = *(const uint4*)&Wt_lo[(size_t)c * K + k0 + q];
            }
        }
        __syncthreads();
        bf16x8 ah[2], al[2];
#pragma unroll
        for (int i = 0; i < 2; ++i) {
            ah[i] = *(const bf16x8*)&As_hi[wr0 + i * 16 + l15][l4 * 8];
            al[i] = *(const bf16x8*)&As_lo[wr0 + i * 16 + l15][l4 * 8];
        }
#pragma unroll
        for (int j = 0; j < 8; ++j) {
            bf16x8 bh = *(const bf16x8*)&Bs_hi[j * 16 + l15][l4 * 8];
            bf16x8 bl = *(const bf16x8*)&Bs_lo[j * 16 + l15][l4 * 8];
#pragma unroll
            for (int i = 0; i < 2; ++i) {
                acc[i][j] = __builtin_amdgcn_mfma_f32_16x16x32_bf16(ah[i], bh, acc[i][j], 0, 0, 0);
                acc[i][j] = __builtin_amdgcn_mfma_f32_16x16x32_bf16(ah[i], bl, acc[i][j], 0, 0, 0);
                acc[i][j] = __builtin_amdgcn_mfma_f32_16x16x32_bf16(al[i], bh, acc[i][j], 0, 0, 0);
            }
        }
    }
#pragma unroll
    for (int i = 0; i < 2; ++i) {
#pragma unroll
        for (int r = 0; r < 4; ++r) {
            int grow = row0 + wr0 + i * 16 + l4 * 4 + r;
            if (grow < n) {
                float dv = dinv[grow];
#pragma unroll
                for (int j = 0; j < 8; ++j) {
                    G[(size_t)grow * 128 + j * 16 + l15] = acc[i][j][r] * dv;
                }
            }
        }
    }
}

// ---------------- Aggregation ----------------
__global__ __launch_bounds__(256) void aggregate_kernel(const float* __restrict__ G,
                                                        const int* __restrict__ offs,
                                                        const int* __restrict__ srt,
                                                        const float* __restrict__ dinv,
                                                        const float* __restrict__ bias,
                                                        float* __restrict__ H, int n, int do_relu) {
    int wid = (blockIdx.x * blockDim.x + threadIdx.x) >> 6;
    int lane = threadIdx.x & 63;
    if (wid >= n) return;
    int hh = lane >> 5;
    int c4 = (lane & 31) * 4;
    int beg = offs[wid], end = offs[wid + 1];
    float4 a = make_float4(0.f, 0.f, 0.f, 0.f);
    if (!hh) a = *(const float4*)&G[(size_t)wid * 128 + c4];
    int e = beg + hh;
    for (; e + 6 < end; e += 8) {
        int s0 = srt[e], s1 = srt[e + 2], s2 = srt[e + 4], s3 = srt[e + 6];
        float4 v0 = *(const float4*)&G[(size_t)s0 * 128 + c4];
        float4 v1 = *(const float4*)&G[(size_t)s1 * 128 + c4];
        float4 v2 = *(const float4*)&G[(size_t)s2 * 128 + c4];
        float4 v3 = *(const float4*)&G[(size_t)s3 * 128 + c4];
        a.x += v0.x + v1.x + v2.x + v3.x;
        a.y += v0.y + v1.y + v2.y + v3.y;
        a.z += v0.z + v1.z + v2.z + v3.z;
        a.w += v0.w + v1.w + v2.w + v3.w;
    }
    for (; e < end; e += 2) {
        int s = srt[e];
        float4 v = *(const float4*)&G[(size_t)s * 128 + c4];
        a.x += v.x; a.y += v.y; a.z += v.z; a.w += v.w;
    }
    a.x += __shfl_xor(a.x, 32);
    a.y += __shfl_xor(a.y, 32);
    a.z += __shfl_xor(a.z, 32);
    a.w += __shfl_xor(a.w, 32);
    if (!hh) {
        float dv = dinv[wid];
        float4 b = *(const float4*)&bias[c4];
        float4 r;
        r.x = a.x * dv + b.x;
        r.y = a.y * dv + b.y;
        r.z = a.z * dv + b.z;
        r.w = a.w * dv + b.w;
        if (do_relu) {
            r.x = fmaxf(r.x, 0.f); r.y = fmaxf(r.y, 0.f);
            r.z = fmaxf(r.z, 0.f); r.w = fmaxf(r.w, 0.f);
        }
        *(float4*)&H[(size_t)wid * 128 + c4] = r;
    }
}

// ---------------- Layer-3 tiny GEMM ----------------
__global__ __launch_bounds__(256) void gemm_c2_kernel(const float* __restrict__ H,
                                                      const float* __restrict__ Wc,
                                                      const float* __restrict__ dinv,
                                                      float* __restrict__ G3, int n) {
    int wid = (blockIdx.x * blockDim.x + threadIdx.x) >> 6;
    int lane = threadIdx.x & 63;
    if (wid >= n) return;
    float2 h = *(const float2*)&H[(size_t)wid * 128 + lane * 2];
    float w00 = Wc[lane * 4 + 0];
    float w01 = Wc[lane * 4 + 1];
    float w10 = Wc[lane * 4 + 2];
    float w11 = Wc[lane * 4 + 3];
    float p0 = h.x * w00 + h.y * w10;
    float p1 = h.x * w01 + h.y * w11;
    for (int off = 32; off > 0; off >>= 1) {
        p0 += __shfl_xor(p0, off);
        p1 += __shfl_xor(p1, off);
    }
    if (lane == 0) {
        float dv = dinv[wid];
        G3[(size_t)wid * 2 + 0] = p0 * dv;
        G3[(size_t)wid * 2 + 1] = p1 * dv;
    }
}

__global__ __launch_bounds__(64) void final_kernel(const float* __restrict__ G3,
                                                   const int* __restrict__ ptr,
                                                   const int* __restrict__ offs,
                                                   const int* __restrict__ srt,
                                                   const float* __restrict__ dinv,
                                                   const float* __restrict__ bc,
                                                   float* __restrict__ out, int ngraphs) {
    int i = blockIdx.x;
    if (i >= ngraphs) return;
    int v = ptr[i];
    int lane = threadIdx.x;
    float p0 = 0.f, p1 = 0.f;
    int beg = offs[v], end = offs[v + 1];
    for (int e = beg + lane; e < end; e += 64) {
        int s = srt[e];
        p0 += G3[(size_t)s * 2 + 0];
        p1 += G3[(size_t)s * 2 + 1];
    }
    for (int off = 32; off > 0; off >>= 1) {
        p0 += __shfl_xor(p0, off);
        p1 += __shfl_xor(p1, off);
    }
    if (lane == 0) {
        p0 += G3[(size_t)v * 2 + 0];
        p1 += G3[(size_t)v * 2 + 1];
        float dv = dinv[v];
        out[i * 2 + 0] = p0 * dv + bc[0];
        out[i * 2 + 1] = p1 * dv + bc[1];
    }
}

extern "C" void kernel_launch(void* const* d_in, const int* in_sizes, int n_in,
                              void* d_out, int out_size, void* d_ws, size_t ws_size,
                              hipStream_t stream) {
    const float* x  = (const float*)d_in[0];
    const int* ei   = (const int*)d_in[1];
    const int* ptr  = (const int*)d_in[2];
    const float* W1 = (const float*)d_in[3];
    const float* b1 = (const float*)d_in[4];
    const float* W2 = (const float*)d_in[5];
    const float* b2 = (const float*)d_in[6];
    const float* Wc = (const float*)d_in[7];
    const float* bc = (const float*)d_in[8];
    float* out = (float*)d_out;

    const int IN_DIM = 768, HID = 128;
    const int NN = in_sizes[0] / IN_DIM;     // 100000
    const int E  = in_sizes[1] / 2;          // 3200000
    const int NG = in_sizes[2] - 1;          // 512
    const int NB = (NN + 127) >> 7;          // buckets of 128 nodes

    char* ws = (char*)d_ws;
    size_t off = 0;
    auto alloc = [&](size_t bytes) -> void* {
        void* p = ws + off;
        off += (bytes + 255) & ~(size_t)255;
        return p;
    };
    float* dinv   = (float*)alloc((size_t)NN * 4);
    int*   offs   = (int*)alloc((size_t)(NN + 1) * 4);
    int*   bcnt   = (int*)alloc((size_t)(NB + 1) * 4);
    int*   bbase  = (int*)alloc((size_t)(NB + 1) * 4);
    int*   bcur   = (int*)alloc((size_t)NB * 4);
    int*   srt    = (int*)alloc((size_t)E * 4);
    float* G      = (float*)alloc((size_t)NN * HID * 4);
    float* H      = (float*)alloc((size_t)NN * HID * 4);
    float* G3     = (float*)alloc((size_t)NN * 2 * 4);
    unsigned short* Wt1_hi = (unsigned short*)alloc((size_t)IN_DIM * HID * 2);
    unsigned short* Wt1_lo = (unsigned short*)alloc((size_t)IN_DIM * HID * 2);
    unsigned short* Wt2_hi = (unsigned short*)alloc((size_t)HID * HID * 2);
    unsigned short* Wt2_lo = (unsigned short*)alloc((size_t)HID * HID * 2);

    // epk aliases G: only live during CSR build, G first written by layer-1 gemm
    unsigned long long* epk = (unsigned long long*)G;

    (void)n_in; (void)out_size; (void)ws_size;

    hipMemsetAsync(bcnt, 0, (size_t)(NB + 1) * 4, stream);
    bucket_hist<<<512, 256, 0, stream>>>(ei, bcnt, E, NB);
    bucket_scan<<<1, 1024, 0, stream>>>(bcnt, bbase, bcur, offs, NB, NN, E);
    bucket_scatter<<<2048, 256, 0, stream>>>(ei, bcur, epk, E);
    bucket_build<<<NB, 256, 0, stream>>>(epk, bbase, offs, dinv, srt, NN);

    wt_prep<<<(IN_DIM * HID + 255) / 256, 256, 0, stream>>>(W1, Wt1_hi, Wt1_lo, IN_DIM);
    wt_prep<<<(HID * HID + 255) / 256, 256, 0, stream>>>(W2, Wt2_hi, Wt2_lo, HID);

    int gblocks = (NN + 127) / 128;
    int agg_blocks = (NN * 64 + 255) / 256;

    // layer 1
    gemm_mfma<768><<<gblocks, 256, 0, stream>>>(x, Wt1_hi, Wt1_lo, dinv, G, NN);
    aggregate_kernel<<<agg_blocks, 256, 0, stream>>>(G, offs, srt, dinv, b1, H, NN, 1);
    // layer 2
    gemm_mfma<128><<<gblocks, 256, 0, stream>>>(H, Wt2_hi, Wt2_lo, dinv, G, NN);
    aggregate_kernel<<<agg_blocks, 256, 0, stream>>>(G, offs, srt, dinv, b2, H, NN, 1);
    // layer 3
    gemm_c2_kernel<<<agg_blocks, 256, 0, stream>>>(H, Wc, dinv, G3, NN);
    final_kernel<<<NG, 64, 0, stream>>>(G3, ptr, offs, srt, dinv, bc, out, NG);
}

// Round 4
// 737.831 us; speedup vs baseline: 1.9282x; 1.9282x over previous
//
#include <hip/hip_runtime.h>

typedef short bf16x8 __attribute__((ext_vector_type(8)));
typedef float f32x4 __attribute__((ext_vector_type(4)));

__device__ __forceinline__ unsigned short f2bf_rn(float x) {
    unsigned int u = __float_as_uint(x);
    unsigned int r = u + 0x7FFF + ((u >> 16) & 1);
    return (unsigned short)(r >> 16);
}
__device__ __forceinline__ float bf2f(unsigned short h) {
    return __uint_as_float(((unsigned int)h) << 16);
}

// ================= Bucketed CSR build =================
// bucket b = dst >> 7 (128 nodes per bucket). NB <= 1024.

__global__ __launch_bounds__(256) void bucket_hist(const int* __restrict__ ei,
                                                   int* __restrict__ bcnt, int E, int NB) {
    __shared__ int h[1024];
    for (int i = threadIdx.x; i < NB; i += 256) h[i] = 0;
    __syncthreads();
    for (int e = blockIdx.x * blockDim.x + threadIdx.x; e < E; e += gridDim.x * blockDim.x) {
        atomicAdd(&h[ei[E + e] >> 7], 1);
    }
    __syncthreads();
    for (int i = threadIdx.x; i < NB; i += 256) {
        int v = h[i];
        if (v) atomicAdd(&bcnt[i], v);
    }
}

// single block: exclusive scan of bcnt[NB] -> bbase, init bcur, set sentinels
__global__ __launch_bounds__(1024) void bucket_scan(const int* __restrict__ bcnt,
                                                    int* __restrict__ bbase,
                                                    int* __restrict__ bcur,
                                                    int* __restrict__ offs,
                                                    int NB, int NN, int E) {
    __shared__ int s[1024];
    int t = threadIdx.x;
    int v = (t < NB) ? bcnt[t] : 0;
    s[t] = v;
    __syncthreads();
    for (int off = 1; off < 1024; off <<= 1) {
        int u = (t >= off) ? s[t - off] : 0;
        __syncthreads();
        s[t] += u;
        __syncthreads();
    }
    if (t < NB) {
        int base = s[t] - v;     // exclusive
        bbase[t] = base;
        bcur[t] = base;
    }
    if (t == 0) {
        bbase[NB] = E;
        offs[NN] = E;
    }
}

// two-pass block-local scatter: LDS histogram -> one global atomic per (block,bucket)
// -> LDS-cursor placement. epk[p] = (dst&127)<<17 | src   (src < 2^17)
__global__ __launch_bounds__(256) void bucket_scatter(const int* __restrict__ ei,
                                                      int* __restrict__ bcur,
                                                      unsigned int* __restrict__ epk,
                                                      int E, int NB) {
    __shared__ int hist[1024];
    __shared__ int cur[1024];
    int tid = threadIdx.x;
    int chunk = (E + gridDim.x - 1) / gridDim.x;
    int beg = blockIdx.x * chunk;
    int end = beg + chunk; if (end > E) end = E;
    for (int i = tid; i < NB; i += 256) hist[i] = 0;
    __syncthreads();
    for (int e = beg + tid; e < end; e += 256) {
        atomicAdd(&hist[ei[E + e] >> 7], 1);
    }
    __syncthreads();
    for (int i = tid; i < NB; i += 256) {
        int c = hist[i];
        cur[i] = c ? atomicAdd(&bcur[i], c) : 0;
    }
    __syncthreads();
    for (int e = beg + tid; e < end; e += 256) {
        int s = ei[e];
        int d = ei[E + e];
        int p = atomicAdd(&cur[d >> 7], 1);
        epk[p] = ((unsigned)(d & 127) << 17) | (unsigned)s;
    }
}

// one block per bucket: local histogram + scan -> offs/dinv, then ordered srt writes
__global__ __launch_bounds__(256) void bucket_build(const unsigned int* __restrict__ epk,
                                                    const int* __restrict__ bbase,
                                                    int* __restrict__ offs,
                                                    float* __restrict__ dinv,
                                                    int* __restrict__ srt,
                                                    int NN) {
    __shared__ int lcnt[128];
    __shared__ int sc[128];
    __shared__ int lcur[128];
    int b = blockIdx.x;
    int tid = threadIdx.x;
    int base = bbase[b], endp = bbase[b + 1];
    int ne = endp - base;
    int v0 = b << 7;
    int nv = NN - v0; if (nv > 128) nv = 128;

    if (tid < 128) lcnt[tid] = 0;
    __syncthreads();
    for (int i = tid; i < ne; i += 256) {
        int d = (int)(epk[base + i] >> 17);
        atomicAdd(&lcnt[d], 1);
    }
    __syncthreads();
    if (tid < 128) sc[tid] = lcnt[tid];
    __syncthreads();
    for (int off = 1; off < 128; off <<= 1) {
        int u = (tid < 128 && tid >= off) ? sc[tid - off] : 0;
        __syncthreads();
        if (tid < 128) sc[tid] += u;
        __syncthreads();
    }
    if (tid < nv) {
        int ex = sc[tid] - lcnt[tid];
        offs[v0 + tid] = base + ex;
        lcur[tid] = base + ex;
        dinv[v0 + tid] = rsqrtf((float)(lcnt[tid] + 1));
    }
    __syncthreads();
    for (int i = tid; i < ne; i += 256) {
        unsigned int pk = epk[base + i];
        int d = (int)(pk >> 17);
        int s = (int)(pk & 0x1FFFFu);
        int p = atomicAdd(&lcur[d], 1);
        srt[p] = s;
    }
}

// ---------------- W pre-split: W[K][128] fp32 -> Wt_hi/Wt_lo[col][K] bf16 ----------------
__global__ void wt_prep(const float* __restrict__ W, unsigned short* __restrict__ hi,
                        unsigned short* __restrict__ lo, int K) {
    int idx = blockIdx.x * 256 + threadIdx.x;
    if (idx >= K * 128) return;
    int k = idx >> 7;
    int c = idx & 127;
    float x = W[idx];
    unsigned short h = f2bf_rn(x);
    unsigned short l = f2bf_rn(x - bf2f(h));
    hi[(size_t)c * K + k] = h;
    lo[(size_t)c * K + k] = l;
}

// ---------------- MFMA GEMM (split-bf16): G = (X@W) * dinv[row] ----------------
template <int K>
__global__ __launch_bounds__(256) void gemm_mfma(const float* __restrict__ X,
                                                 const unsigned short* __restrict__ Wt_hi,
                                                 const unsigned short* __restrict__ Wt_lo,
                                                 const float* __restrict__ dinv,
                                                 float* __restrict__ G, int n) {
    __shared__ unsigned short As_hi[128][40];
    __shared__ unsigned short As_lo[128][40];
    __shared__ unsigned short Bs_hi[128][40];
    __shared__ unsigned short Bs_lo[128][40];

    const int tid = threadIdx.x;
    const int wave = tid >> 6;
    const int lane = tid & 63;
    const int l15 = lane & 15;
    const int l4 = lane >> 4;
    const int row0 = blockIdx.x * 128;
    const int wr0 = wave * 32;

    f32x4 acc[2][8];
#pragma unroll
    for (int i = 0; i < 2; ++i)
#pragma unroll
        for (int j = 0; j < 8; ++j) acc[i][j] = (f32x4){0.f, 0.f, 0.f, 0.f};

    const int sr = tid >> 1;
    const int sf = (tid & 1) * 16;

    for (int k0 = 0; k0 < K; k0 += 32) {
        __syncthreads();
        {
            int grow = row0 + sr;
            float4 v[4];
            if (grow < n) {
                const float* src = X + (size_t)grow * K + k0 + sf;
#pragma unroll
                for (int g = 0; g < 4; ++g) v[g] = *(const float4*)(src + g * 4);
            } else {
#pragma unroll
                for (int g = 0; g < 4; ++g) v[g] = make_float4(0.f, 0.f, 0.f, 0.f);
            }
#pragma unroll
            for (int g = 0; g < 4; ++g) {
                ushort4 h, l;
                h.x = f2bf_rn(v[g].x); l.x = f2bf_rn(v[g].x - bf2f(h.x));
                h.y = f2bf_rn(v[g].y); l.y = f2bf_rn(v[g].y - bf2f(h.y));
                h.z = f2bf_rn(v[g].z); l.z = f2bf_rn(v[g].z - bf2f(h.z));
                h.w = f2bf_rn(v[g].w); l.w = f2bf_rn(v[g].w - bf2f(h.w));
                *(ushort4*)&As_hi[sr][sf + g * 4] = h;
                *(ushort4*)&As_lo[sr][sf + g * 4] = l;
            }
        }
        {
#pragma unroll
            for (int rep = 0; rep < 2; ++rep) {
                int id = tid + rep * 256;
                int c = id >> 2;
                int q = (id & 3) * 8;
                *(uint4*)&Bs_hi[c][q] = *(const uint4*)&Wt_hi[(size_t)c * K + k0 + q];
                *(uint4*)&Bs_lo[c][q] = *(const uint4*)&Wt_lo[(size_t)c * K + k0 + q];
            }
        }
        __syncthreads();
        bf16x8 ah[2], al[2];
#pragma unroll
        for (int i = 0; i < 2; ++i) {
            ah[i] = *(const bf16x8*)&As_hi[wr0 + i * 16 + l15][l4 * 8];
            al[i] = *(const bf16x8*)&As_lo[wr0 + i * 16 + l15][l4 * 8];
        }
#pragma unroll
        for (int j = 0; j < 8; ++j) {
            bf16x8 bh = *(const bf16x8*)&Bs_hi[j * 16 + l15][l4 * 8];
            bf16x8 bl = *(const bf16x8*)&Bs_lo[j * 16 + l15][l4 * 8];
#pragma unroll
            for (int i = 0; i < 2; ++i) {
                acc[i][j] = __builtin_amdgcn_mfma_f32_16x16x32_bf16(ah[i], bh, acc[i][j], 0, 0, 0);
                acc[i][j] = __builtin_amdgcn_mfma_f32_16x16x32_bf16(ah[i], bl, acc[i][j], 0, 0, 0);
                acc[i][j] = __builtin_amdgcn_mfma_f32_16x16x32_bf16(al[i], bh, acc[i][j], 0, 0, 0);
            }
        }
    }
#pragma unroll
    for (int i = 0; i < 2; ++i) {
#pragma unroll
        for (int r = 0; r < 4; ++r) {
            int grow = row0 + wr0 + i * 16 + l4 * 4 + r;
            if (grow < n) {
                float dv = dinv[grow];
#pragma unroll
                for (int j = 0; j < 8; ++j) {
                    G[(size_t)grow * 128 + j * 16 + l15] = acc[i][j][r] * dv;
                }
            }
        }
    }
}

// ---------------- Aggregation ----------------
__global__ __launch_bounds__(256) void aggregate_kernel(const float* __restrict__ G,
                                                        const int* __restrict__ offs,
                                                        const int* __restrict__ srt,
                                                        const float* __restrict__ dinv,
                                                        const float* __restrict__ bias,
                                                        float* __restrict__ H, int n, int do_relu) {
    int wid = (blockIdx.x * blockDim.x + threadIdx.x) >> 6;
    int lane = threadIdx.x & 63;
    if (wid >= n) return;
    int hh = lane >> 5;
    int c4 = (lane & 31) * 4;
    int beg = offs[wid], end = offs[wid + 1];
    float4 a = make_float4(0.f, 0.f, 0.f, 0.f);
    if (!hh) a = *(const float4*)&G[(size_t)wid * 128 + c4];
    int e = beg + hh;
    for (; e + 6 < end; e += 8) {
        int s0 = srt[e], s1 = srt[e + 2], s2 = srt[e + 4], s3 = srt[e + 6];
        float4 v0 = *(const float4*)&G[(size_t)s0 * 128 + c4];
        float4 v1 = *(const float4*)&G[(size_t)s1 * 128 + c4];
        float4 v2 = *(const float4*)&G[(size_t)s2 * 128 + c4];
        float4 v3 = *(const float4*)&G[(size_t)s3 * 128 + c4];
        a.x += v0.x + v1.x + v2.x + v3.x;
        a.y += v0.y + v1.y + v2.y + v3.y;
        a.z += v0.z + v1.z + v2.z + v3.z;
        a.w += v0.w + v1.w + v2.w + v3.w;
    }
    for (; e < end; e += 2) {
        int s = srt[e];
        float4 v = *(const float4*)&G[(size_t)s * 128 + c4];
        a.x += v.x; a.y += v.y; a.z += v.z; a.w += v.w;
    }
    a.x += __shfl_xor(a.x, 32);
    a.y += __shfl_xor(a.y, 32);
    a.z += __shfl_xor(a.z, 32);
    a.w += __shfl_xor(a.w, 32);
    if (!hh) {
        float dv = dinv[wid];
        float4 b = *(const float4*)&bias[c4];
        float4 r;
        r.x = a.x * dv + b.x;
        r.y = a.y * dv + b.y;
        r.z = a.z * dv + b.z;
        r.w = a.w * dv + b.w;
        if (do_relu) {
            r.x = fmaxf(r.x, 0.f); r.y = fmaxf(r.y, 0.f);
            r.z = fmaxf(r.z, 0.f); r.w = fmaxf(r.w, 0.f);
        }
        *(float4*)&H[(size_t)wid * 128 + c4] = r;
    }
}

// ---------------- Layer-3 tiny GEMM ----------------
__global__ __launch_bounds__(256) void gemm_c2_kernel(const float* __restrict__ H,
                                                      const float* __restrict__ Wc,
                                                      const float* __restrict__ dinv,
                                                      float* __restrict__ G3, int n) {
    int wid = (blockIdx.x * blockDim.x + threadIdx.x) >> 6;
    int lane = threadIdx.x & 63;
    if (wid >= n) return;
    float2 h = *(const float2*)&H[(size_t)wid * 128 + lane * 2];
    float w00 = Wc[lane * 4 + 0];
    float w01 = Wc[lane * 4 + 1];
    float w10 = Wc[lane * 4 + 2];
    float w11 = Wc[lane * 4 + 3];
    float p0 = h.x * w00 + h.y * w10;
    float p1 = h.x * w01 + h.y * w11;
    for (int off = 32; off > 0; off >>= 1) {
        p0 += __shfl_xor(p0, off);
        p1 += __shfl_xor(p1, off);
    }
    if (lane == 0) {
        float dv = dinv[wid];
        G3[(size_t)wid * 2 + 0] = p0 * dv;
        G3[(size_t)wid * 2 + 1] = p1 * dv;
    }
}

__global__ __launch_bounds__(64) void final_kernel(const float* __restrict__ G3,
                                                   const int* __restrict__ ptr,
                                                   const int* __restrict__ offs,
                                                   const int* __restrict__ srt,
                                                   const float* __restrict__ dinv,
                                                   const float* __restrict__ bc,
                                                   float* __restrict__ out, int ngraphs) {
    int i = blockIdx.x;
    if (i >= ngraphs) return;
    int v = ptr[i];
    int lane = threadIdx.x;
    float p0 = 0.f, p1 = 0.f;
    int beg = offs[v], end = offs[v + 1];
    for (int e = beg + lane; e < end; e += 64) {
        int s = srt[e];
        p0 += G3[(size_t)s * 2 + 0];
        p1 += G3[(size_t)s * 2 + 1];
    }
    for (int off = 32; off > 0; off >>= 1) {
        p0 += __shfl_xor(p0, off);
        p1 += __shfl_xor(p1, off);
    }
    if (lane == 0) {
        p0 += G3[(size_t)v * 2 + 0];
        p1 += G3[(size_t)v * 2 + 1];
        float dv = dinv[v];
        out[i * 2 + 0] = p0 * dv + bc[0];
        out[i * 2 + 1] = p1 * dv + bc[1];
    }
}

extern "C" void kernel_launch(void* const* d_in, const int* in_sizes, int n_in,
                              void* d_out, int out_size, void* d_ws, size_t ws_size,
                              hipStream_t stream) {
    const float* x  = (const float*)d_in[0];
    const int* ei   = (const int*)d_in[1];
    const int* ptr  = (const int*)d_in[2];
    const float* W1 = (const float*)d_in[3];
    const float* b1 = (const float*)d_in[4];
    const float* W2 = (const float*)d_in[5];
    const float* b2 = (const float*)d_in[6];
    const float* Wc = (const float*)d_in[7];
    const float* bc = (const float*)d_in[8];
    float* out = (float*)d_out;

    const int IN_DIM = 768, HID = 128;
    const int NN = in_sizes[0] / IN_DIM;     // 100000
    const int E  = in_sizes[1] / 2;          // 3200000
    const int NG = in_sizes[2] - 1;          // 512
    const int NB = (NN + 127) >> 7;          // buckets of 128 nodes

    char* ws = (char*)d_ws;
    size_t off = 0;
    auto alloc = [&](size_t bytes) -> void* {
        void* p = ws + off;
        off += (bytes + 255) & ~(size_t)255;
        return p;
    };
    float* dinv   = (float*)alloc((size_t)NN * 4);
    int*   offs   = (int*)alloc((size_t)(NN + 1) * 4);
    int*   bcnt   = (int*)alloc((size_t)(NB + 1) * 4);
    int*   bbase  = (int*)alloc((size_t)(NB + 1) * 4);
    int*   bcur   = (int*)alloc((size_t)NB * 4);
    int*   srt    = (int*)alloc((size_t)E * 4);
    float* G      = (float*)alloc((size_t)NN * HID * 4);
    float* H      = (float*)alloc((size_t)NN * HID * 4);
    float* G3     = (float*)alloc((size_t)NN * 2 * 4);
    unsigned short* Wt1_hi = (unsigned short*)alloc((size_t)IN_DIM * HID * 2);
    unsigned short* Wt1_lo = (unsigned short*)alloc((size_t)IN_DIM * HID * 2);
    unsigned short* Wt2_hi = (unsigned short*)alloc((size_t)HID * HID * 2);
    unsigned short* Wt2_lo = (unsigned short*)alloc((size_t)HID * HID * 2);

    // epk aliases G: only live during CSR build, G first written by layer-1 gemm
    unsigned int* epk = (unsigned int*)G;

    (void)n_in; (void)out_size; (void)ws_size;

    hipMemsetAsync(bcnt, 0, (size_t)(NB + 1) * 4, stream);
    bucket_hist<<<512, 256, 0, stream>>>(ei, bcnt, E, NB);
    bucket_scan<<<1, 1024, 0, stream>>>(bcnt, bbase, bcur, offs, NB, NN, E);
    bucket_scatter<<<256, 256, 0, stream>>>(ei, bcur, epk, E, NB);
    bucket_build<<<NB, 256, 0, stream>>>(epk, bbase, offs, dinv, srt, NN);

    wt_prep<<<(IN_DIM * HID + 255) / 256, 256, 0, stream>>>(W1, Wt1_hi, Wt1_lo, IN_DIM);
    wt_prep<<<(HID * HID + 255) / 256, 256, 0, stream>>>(W2, Wt2_hi, Wt2_lo, HID);

    int gblocks = (NN + 127) / 128;
    int agg_blocks = (NN * 64 + 255) / 256;

    // layer 1
    gemm_mfma<768><<<gblocks, 256, 0, stream>>>(x, Wt1_hi, Wt1_lo, dinv, G, NN);
    aggregate_kernel<<<agg_blocks, 256, 0, stream>>>(G, offs, srt, dinv, b1, H, NN, 1);
    // layer 2
    gemm_mfma<128><<<gblocks, 256, 0, stream>>>(H, Wt2_hi, Wt2_lo, dinv, G, NN);
    aggregate_kernel<<<agg_blocks, 256, 0, stream>>>(G, offs, srt, dinv, b2, H, NN, 1);
    // layer 3
    gemm_c2_kernel<<<agg_blocks, 256, 0, stream>>>(H, Wc, dinv, G3, NN);
    final_kernel<<<NG, 64, 0, stream>>>(G3, ptr, offs, srt, dinv, bc, out, NG);
}

// Round 5
// 520.120 us; speedup vs baseline: 2.7353x; 1.4186x over previous
//
#include <hip/hip_runtime.h>

typedef short bf16x8 __attribute__((ext_vector_type(8)));
typedef float f32x4 __attribute__((ext_vector_type(4)));
typedef _Float16 f16x4 __attribute__((ext_vector_type(4)));

__device__ __forceinline__ unsigned short f2bf_rn(float x) {
    unsigned int u = __float_as_uint(x);
    unsigned int r = u + 0x7FFF + ((u >> 16) & 1);
    return (unsigned short)(r >> 16);
}
__device__ __forceinline__ float bf2f(unsigned short h) {
    return __uint_as_float(((unsigned int)h) << 16);
}

// ================= Bucketed CSR build =================
// bucket b = dst >> 7 (128 nodes per bucket). NB <= 1024.

__global__ __launch_bounds__(256) void bucket_hist(const int* __restrict__ ei,
                                                   int* __restrict__ bcnt, int E, int NB) {
    __shared__ int h[1024];
    for (int i = threadIdx.x; i < NB; i += 256) h[i] = 0;
    __syncthreads();
    for (int e = blockIdx.x * blockDim.x + threadIdx.x; e < E; e += gridDim.x * blockDim.x) {
        atomicAdd(&h[ei[E + e] >> 7], 1);
    }
    __syncthreads();
    for (int i = threadIdx.x; i < NB; i += 256) {
        int v = h[i];
        if (v) atomicAdd(&bcnt[i], v);
    }
}

__global__ __launch_bounds__(1024) void bucket_scan(const int* __restrict__ bcnt,
                                                    int* __restrict__ bbase,
                                                    int* __restrict__ bcur,
                                                    int* __restrict__ offs,
                                                    int NB, int NN, int E) {
    __shared__ int s[1024];
    int t = threadIdx.x;
    int v = (t < NB) ? bcnt[t] : 0;
    s[t] = v;
    __syncthreads();
    for (int off = 1; off < 1024; off <<= 1) {
        int u = (t >= off) ? s[t - off] : 0;
        __syncthreads();
        s[t] += u;
        __syncthreads();
    }
    if (t < NB) {
        int base = s[t] - v;
        bbase[t] = base;
        bcur[t] = base;
    }
    if (t == 0) {
        bbase[NB] = E;
        offs[NN] = E;
    }
}

// two-pass block-local scatter: LDS histogram -> one global atomic per (block,bucket)
// -> LDS-cursor placement. epk[p] = (dst&127)<<17 | src   (src < 2^17)
__global__ __launch_bounds__(256) void bucket_scatter(const int* __restrict__ ei,
                                                      int* __restrict__ bcur,
                                                      unsigned int* __restrict__ epk,
                                                      int E, int NB) {
    __shared__ int hist[1024];
    __shared__ int cur[1024];
    int tid = threadIdx.x;
    int chunk = (E + gridDim.x - 1) / gridDim.x;
    int beg = blockIdx.x * chunk;
    int end = beg + chunk; if (end > E) end = E;
    for (int i = tid; i < NB; i += 256) hist[i] = 0;
    __syncthreads();
    for (int e = beg + tid; e < end; e += 256) {
        atomicAdd(&hist[ei[E + e] >> 7], 1);
    }
    __syncthreads();
    for (int i = tid; i < NB; i += 256) {
        int c = hist[i];
        cur[i] = c ? atomicAdd(&bcur[i], c) : 0;
    }
    __syncthreads();
    for (int e = beg + tid; e < end; e += 256) {
        int s = ei[e];
        int d = ei[E + e];
        int p = atomicAdd(&cur[d >> 7], 1);
        epk[p] = ((unsigned)(d & 127) << 17) | (unsigned)s;
    }
}

__global__ __launch_bounds__(256) void bucket_build(const unsigned int* __restrict__ epk,
                                                    const int* __restrict__ bbase,
                                                    int* __restrict__ offs,
                                                    float* __restrict__ dinv,
                                                    int* __restrict__ srt,
                                                    int NN) {
    __shared__ int lcnt[128];
    __shared__ int sc[128];
    __shared__ int lcur[128];
    int b = blockIdx.x;
    int tid = threadIdx.x;
    int base = bbase[b], endp = bbase[b + 1];
    int ne = endp - base;
    int v0 = b << 7;
    int nv = NN - v0; if (nv > 128) nv = 128;

    if (tid < 128) lcnt[tid] = 0;
    __syncthreads();
    for (int i = tid; i < ne; i += 256) {
        int d = (int)(epk[base + i] >> 17);
        atomicAdd(&lcnt[d], 1);
    }
    __syncthreads();
    if (tid < 128) sc[tid] = lcnt[tid];
    __syncthreads();
    for (int off = 1; off < 128; off <<= 1) {
        int u = (tid < 128 && tid >= off) ? sc[tid - off] : 0;
        __syncthreads();
        if (tid < 128) sc[tid] += u;
        __syncthreads();
    }
    if (tid < nv) {
        int ex = sc[tid] - lcnt[tid];
        offs[v0 + tid] = base + ex;
        lcur[tid] = base + ex;
        dinv[v0 + tid] = rsqrtf((float)(lcnt[tid] + 1));
    }
    __syncthreads();
    for (int i = tid; i < ne; i += 256) {
        unsigned int pk = epk[base + i];
        int d = (int)(pk >> 17);
        int s = (int)(pk & 0x1FFFFu);
        int p = atomicAdd(&lcur[d], 1);
        srt[p] = s;
    }
}

// ---------------- W pre-split: W[K][128] fp32 -> Wt_hi/Wt_lo[col][K] bf16 ----------------
__global__ void wt_prep(const float* __restrict__ W, unsigned short* __restrict__ hi,
                        unsigned short* __restrict__ lo, int K) {
    int idx = blockIdx.x * 256 + threadIdx.x;
    if (idx >= K * 128) return;
    int k = idx >> 7;
    int c = idx & 127;
    float x = W[idx];
    unsigned short h = f2bf_rn(x);
    unsigned short l = f2bf_rn(x - bf2f(h));
    hi[(size_t)c * K + k] = h;
    lo[(size_t)c * K + k] = l;
}

// ---------------- MFMA GEMM (split-bf16): G(fp16) = (X@W) * dinv[row] ----------------
template <int K>
__global__ __launch_bounds__(256) void gemm_mfma(const float* __restrict__ X,
                                                 const unsigned short* __restrict__ Wt_hi,
                                                 const unsigned short* __restrict__ Wt_lo,
                                                 const float* __restrict__ dinv,
                                                 _Float16* __restrict__ G, int n) {
    __shared__ unsigned short As_hi[128][40];
    __shared__ unsigned short As_lo[128][40];
    __shared__ unsigned short Bs_hi[128][40];
    __shared__ unsigned short Bs_lo[128][40];

    const int tid = threadIdx.x;
    const int wave = tid >> 6;
    const int lane = tid & 63;
    const int l15 = lane & 15;
    const int l4 = lane >> 4;
    const int row0 = blockIdx.x * 128;
    const int wr0 = wave * 32;

    f32x4 acc[2][8];
#pragma unroll
    for (int i = 0; i < 2; ++i)
#pragma unroll
        for (int j = 0; j < 8; ++j) acc[i][j] = (f32x4){0.f, 0.f, 0.f, 0.f};

    const int sr = tid >> 1;
    const int sf = (tid & 1) * 16;

    for (int k0 = 0; k0 < K; k0 += 32) {
        __syncthreads();
        {
            int grow = row0 + sr;
            float4 v[4];
            if (grow < n) {
                const float* src = X + (size_t)grow * K + k0 + sf;
#pragma unroll
                for (int g = 0; g < 4; ++g) v[g] = *(const float4*)(src + g * 4);
            } else {
#pragma unroll
                for (int g = 0; g < 4; ++g) v[g] = make_float4(0.f, 0.f, 0.f, 0.f);
            }
#pragma unroll
            for (int g = 0; g < 4; ++g) {
                ushort4 h, l;
                h.x = f2bf_rn(v[g].x); l.x = f2bf_rn(v[g].x - bf2f(h.x));
                h.y = f2bf_rn(v[g].y); l.y = f2bf_rn(v[g].y - bf2f(h.y));
                h.z = f2bf_rn(v[g].z); l.z = f2bf_rn(v[g].z - bf2f(h.z));
                h.w = f2bf_rn(v[g].w); l.w = f2bf_rn(v[g].w - bf2f(h.w));
                *(ushort4*)&As_hi[sr][sf + g * 4] = h;
                *(ushort4*)&As_lo[sr][sf + g * 4] = l;
            }
        }
        {
#pragma unroll
            for (int rep = 0; rep < 2; ++rep) {
                int id = tid + rep * 256;
                int c = id >> 2;
                int q = (id & 3) * 8;
                *(uint4*)&Bs_hi[c][q] = *(const uint4*)&Wt_hi[(size_t)c * K + k0 + q];
                *(uint4*)&Bs_lo[c][q] = *(const uint4*)&Wt_lo[(size_t)c * K + k0 + q];
            }
        }
        __syncthreads();
        bf16x8 ah[2], al[2];
#pragma unroll
        for (int i = 0; i < 2; ++i) {
            ah[i] = *(const bf16x8*)&As_hi[wr0 + i * 16 + l15][l4 * 8];
            al[i] = *(const bf16x8*)&As_lo[wr0 + i * 16 + l15][l4 * 8];
        }
#pragma unroll
        for (int j = 0; j < 8; ++j) {
            bf16x8 bh = *(const bf16x8*)&Bs_hi[j * 16 + l15][l4 * 8];
            bf16x8 bl = *(const bf16x8*)&Bs_lo[j * 16 + l15][l4 * 8];
#pragma unroll
            for (int i = 0; i < 2; ++i) {
                acc[i][j] = __builtin_amdgcn_mfma_f32_16x16x32_bf16(ah[i], bh, acc[i][j], 0, 0, 0);
                acc[i][j] = __builtin_amdgcn_mfma_f32_16x16x32_bf16(ah[i], bl, acc[i][j], 0, 0, 0);
                acc[i][j] = __builtin_amdgcn_mfma_f32_16x16x32_bf16(al[i], bh, acc[i][j], 0, 0, 0);
            }
        }
    }
#pragma unroll
    for (int i = 0; i < 2; ++i) {
#pragma unroll
        for (int r = 0; r < 4; ++r) {
            int grow = row0 + wr0 + i * 16 + l4 * 4 + r;
            if (grow < n) {
                float dv = dinv[grow];
#pragma unroll
                for (int j = 0; j < 8; ++j) {
                    G[(size_t)grow * 128 + j * 16 + l15] = (_Float16)(acc[i][j][r] * dv);
                }
            }
        }
    }
}

// ---------------- Aggregation: H[v] = relu?(dinv[v]*(sum G[src] + G[v]) + b) ----------------
// G is fp16 [n][128] (256 B/row). One wave per node, half-wave per edge, lane: 4 ch (8 B).
__global__ __launch_bounds__(256) void aggregate_kernel(const _Float16* __restrict__ G,
                                                        const int* __restrict__ offs,
                                                        const int* __restrict__ srt,
                                                        const float* __restrict__ dinv,
                                                        const float* __restrict__ bias,
                                                        float* __restrict__ H, int n, int do_relu) {
    int wid = (blockIdx.x * blockDim.x + threadIdx.x) >> 6;
    int lane = threadIdx.x & 63;
    if (wid >= n) return;
    int hh = lane >> 5;
    int c4 = (lane & 31) * 4;
    int beg = offs[wid], end = offs[wid + 1];
    float ax = 0.f, ay = 0.f, az = 0.f, aw = 0.f;
    if (!hh) {
        f16x4 s = *(const f16x4*)&G[(size_t)wid * 128 + c4];
        ax = (float)s[0]; ay = (float)s[1]; az = (float)s[2]; aw = (float)s[3];
    }
    int e = beg + hh;
    for (; e + 6 < end; e += 8) {
        int s0 = srt[e], s1 = srt[e + 2], s2 = srt[e + 4], s3 = srt[e + 6];
        f16x4 v0 = *(const f16x4*)&G[(size_t)s0 * 128 + c4];
        f16x4 v1 = *(const f16x4*)&G[(size_t)s1 * 128 + c4];
        f16x4 v2 = *(const f16x4*)&G[(size_t)s2 * 128 + c4];
        f16x4 v3 = *(const f16x4*)&G[(size_t)s3 * 128 + c4];
        ax += (float)v0[0] + (float)v1[0] + (float)v2[0] + (float)v3[0];
        ay += (float)v0[1] + (float)v1[1] + (float)v2[1] + (float)v3[1];
        az += (float)v0[2] + (float)v1[2] + (float)v2[2] + (float)v3[2];
        aw += (float)v0[3] + (float)v1[3] + (float)v2[3] + (float)v3[3];
    }
    for (; e < end; e += 2) {
        int s = srt[e];
        f16x4 v = *(const f16x4*)&G[(size_t)s * 128 + c4];
        ax += (float)v[0]; ay += (float)v[1]; az += (float)v[2]; aw += (float)v[3];
    }
    ax += __shfl_xor(ax, 32);
    ay += __shfl_xor(ay, 32);
    az += __shfl_xor(az, 32);
    aw += __shfl_xor(aw, 32);
    if (!hh) {
        float dv = dinv[wid];
        float4 b = *(const float4*)&bias[c4];
        float4 r;
        r.x = ax * dv + b.x;
        r.y = ay * dv + b.y;
        r.z = az * dv + b.z;
        r.w = aw * dv + b.w;
        if (do_relu) {
            r.x = fmaxf(r.x, 0.f); r.y = fmaxf(r.y, 0.f);
            r.z = fmaxf(r.z, 0.f); r.w = fmaxf(r.w, 0.f);
        }
        *(float4*)&H[(size_t)wid * 128 + c4] = r;
    }
}

// ---------------- Layer-3 tiny GEMM ----------------
__global__ __launch_bounds__(256) void gemm_c2_kernel(const float* __restrict__ H,
                                                      const float* __restrict__ Wc,
                                                      const float* __restrict__ dinv,
                                                      float* __restrict__ G3, int n) {
    int wid = (blockIdx.x * blockDim.x + threadIdx.x) >> 6;
    int lane = threadIdx.x & 63;
    if (wid >= n) return;
    float2 h = *(const float2*)&H[(size_t)wid * 128 + lane * 2];
    float w00 = Wc[lane * 4 + 0];
    float w01 = Wc[lane * 4 + 1];
    float w10 = Wc[lane * 4 + 2];
    float w11 = Wc[lane * 4 + 3];
    float p0 = h.x * w00 + h.y * w10;
    float p1 = h.x * w01 + h.y * w11;
    for (int off = 32; off > 0; off >>= 1) {
        p0 += __shfl_xor(p0, off);
        p1 += __shfl_xor(p1, off);
    }
    if (lane == 0) {
        float dv = dinv[wid];
        G3[(size_t)wid * 2 + 0] = p0 * dv;
        G3[(size_t)wid * 2 + 1] = p1 * dv;
    }
}

__global__ __launch_bounds__(64) void final_kernel(const float* __restrict__ G3,
                                                   const int* __restrict__ ptr,
                                                   const int* __restrict__ offs,
                                                   const int* __restrict__ srt,
                                                   const float* __restrict__ dinv,
                                                   const float* __restrict__ bc,
                                                   float* __restrict__ out, int ngraphs) {
    int i = blockIdx.x;
    if (i >= ngraphs) return;
    int v = ptr[i];
    int lane = threadIdx.x;
    float p0 = 0.f, p1 = 0.f;
    int beg = offs[v], end = offs[v + 1];
    for (int e = beg + lane; e < end; e += 64) {
        int s = srt[e];
        p0 += G3[(size_t)s * 2 + 0];
        p1 += G3[(size_t)s * 2 + 1];
    }
    for (int off = 32; off > 0; off >>= 1) {
        p0 += __shfl_xor(p0, off);
        p1 += __shfl_xor(p1, off);
    }
    if (lane == 0) {
        p0 += G3[(size_t)v * 2 + 0];
        p1 += G3[(size_t)v * 2 + 1];
        float dv = dinv[v];
        out[i * 2 + 0] = p0 * dv + bc[0];
        out[i * 2 + 1] = p1 * dv + bc[1];
    }
}

extern "C" void kernel_launch(void* const* d_in, const int* in_sizes, int n_in,
                              void* d_out, int out_size, void* d_ws, size_t ws_size,
                              hipStream_t stream) {
    const float* x  = (const float*)d_in[0];
    const int* ei   = (const int*)d_in[1];
    const int* ptr  = (const int*)d_in[2];
    const float* W1 = (const float*)d_in[3];
    const float* b1 = (const float*)d_in[4];
    const float* W2 = (const float*)d_in[5];
    const float* b2 = (const float*)d_in[6];
    const float* Wc = (const float*)d_in[7];
    const float* bc = (const float*)d_in[8];
    float* out = (float*)d_out;

    const int IN_DIM = 768, HID = 128;
    const int NN = in_sizes[0] / IN_DIM;     // 100000
    const int E  = in_sizes[1] / 2;          // 3200000
    const int NG = in_sizes[2] - 1;          // 512
    const int NB = (NN + 127) >> 7;          // buckets of 128 nodes

    char* ws = (char*)d_ws;
    size_t off = 0;
    auto alloc = [&](size_t bytes) -> void* {
        void* p = ws + off;
        off += (bytes + 255) & ~(size_t)255;
        return p;
    };
    float* dinv   = (float*)alloc((size_t)NN * 4);
    int*   offs   = (int*)alloc((size_t)(NN + 1) * 4);
    int*   bcnt   = (int*)alloc((size_t)(NB + 1) * 4);
    int*   bbase  = (int*)alloc((size_t)(NB + 1) * 4);
    int*   bcur   = (int*)alloc((size_t)NB * 4);
    int*   srt    = (int*)alloc((size_t)E * 4);
    _Float16* G   = (_Float16*)alloc((size_t)NN * HID * 2);
    float* H      = (float*)alloc((size_t)NN * HID * 4);
    float* G3     = (float*)alloc((size_t)NN * 2 * 4);
    unsigned short* Wt1_hi = (unsigned short*)alloc((size_t)IN_DIM * HID * 2);
    unsigned short* Wt1_lo = (unsigned short*)alloc((size_t)IN_DIM * HID * 2);
    unsigned short* Wt2_hi = (unsigned short*)alloc((size_t)HID * HID * 2);
    unsigned short* Wt2_lo = (unsigned short*)alloc((size_t)HID * HID * 2);

    // epk aliases H: only live during CSR build; H first written by layer-1 aggregate
    unsigned int* epk = (unsigned int*)H;

    (void)n_in; (void)out_size; (void)ws_size;

    hipMemsetAsync(bcnt, 0, (size_t)(NB + 1) * 4, stream);
    bucket_hist<<<512, 256, 0, stream>>>(ei, bcnt, E, NB);
    bucket_scan<<<1, 1024, 0, stream>>>(bcnt, bbase, bcur, offs, NB, NN, E);
    bucket_scatter<<<256, 256, 0, stream>>>(ei, bcur, epk, E, NB);
    bucket_build<<<NB, 256, 0, stream>>>(epk, bbase, offs, dinv, srt, NN);

    wt_prep<<<(IN_DIM * HID + 255) / 256, 256, 0, stream>>>(W1, Wt1_hi, Wt1_lo, IN_DIM);
    wt_prep<<<(HID * HID + 255) / 256, 256, 0, stream>>>(W2, Wt2_hi, Wt2_lo, HID);

    int gblocks = (NN + 127) / 128;
    int agg_blocks = (NN * 64 + 255) / 256;

    // layer 1
    gemm_mfma<768><<<gblocks, 256, 0, stream>>>(x, Wt1_hi, Wt1_lo, dinv, G, NN);
    aggregate_kernel<<<agg_blocks, 256, 0, stream>>>(G, offs, srt, dinv, b1, H, NN, 1);
    // layer 2
    gemm_mfma<128><<<gblocks, 256, 0, stream>>>(H, Wt2_hi, Wt2_lo, dinv, G, NN);
    aggregate_kernel<<<agg_blocks, 256, 0, stream>>>(G, offs, srt, dinv, b2, H, NN, 1);
    // layer 3
    gemm_c2_kernel<<<agg_blocks, 256, 0, stream>>>(H, Wc, dinv, G3, NN);
    final_kernel<<<NG, 64, 0, stream>>>(G3, ptr, offs, srt, dinv, bc, out, NG);
}